// Round 13
// baseline (2150.448 us; speedup 1.0000x reference)
//
#include <hip/hip_runtime.h>
#include <cstdint>
#include <cstddef>

#define H_IMG 256
#define W_IMG 320
#define HW_IMG (H_IMG * W_IMG)   // 81920
#define NCLS 22
#define VOTE_STEPS 160
#define TW 64
#define TH 64
#define NTX 5
#define NTY 4
#define NTILE (NTX * NTY)        // 20
#define NCHUNK 16
#define CHPIX (HW_IMG / NCHUNK)  // 5120

// ---------------------------------------------------------------------------
// Weight repack (r3-proven): w[cin][cout][4][4] f32 -> wp[pp][cin][cout][4] f64
// ---------------------------------------------------------------------------
__global__ void repack_kernel(const float* __restrict__ w, double* __restrict__ wp,
                              int CIN, int COUT) {
    int total = CIN * COUT * 16;
    for (int i = blockIdx.x * blockDim.x + threadIdx.x; i < total;
         i += gridDim.x * blockDim.x) {
        int j = i & 3;
        int co = (i >> 2) % COUT;
        int rest = (i >> 2) / COUT;   // pp*CIN + cin
        int cin = rest % CIN;
        int pp = rest / CIN;
        int ry = pp >> 1, rx = pp & 1;
        int dy = j >> 1, dx = j & 1;
        int ky = 3 - ry - 2 * dy;
        int kx = 3 - rx - 2 * dx;
        wp[i] = (double)w[((size_t)cin * COUT + co) * 16 + ky * 4 + kx];
    }
}

// Repack for the 16-cout register-tiled conv: wr[pp][cog][cin][co(16)][tap(4)]
__global__ void repackR_kernel(const float* __restrict__ w, double* __restrict__ wr,
                               int CIN, int COUT) {
    int NCOG = COUT >> 4;
    int total = CIN * COUT * 16;
    for (int i = blockIdx.x * blockDim.x + threadIdx.x; i < total;
         i += gridDim.x * blockDim.x) {
        int tap = i & 3;
        int co = (i >> 2) & 15;
        int rest = i >> 6;            // (pp*NCOG+cog)*CIN + cin
        int cin = rest % CIN;
        int pc = rest / CIN;
        int cog = pc % NCOG;
        int pp = pc / NCOG;
        int ry = pp >> 1, rx = pp & 1;
        int dy = tap >> 1, dxx = tap & 1;
        int ky = 3 - ry - 2 * dy;
        int kx = 3 - rx - 2 * dxx;
        wr[i] = (double)w[((size_t)cin * COUT + (cog * 16 + co)) * 16 + ky * 4 + kx];
    }
}

// w[O][K] f32 -> wt[K][O] f64
__global__ void transpose_d_kernel(const float* __restrict__ w, double* __restrict__ wt,
                                   int O, int K) {
    int i = blockIdx.x * blockDim.x + threadIdx.x;
    if (i < O * K) {
        int o = i / K, k = i - o * K;
        wt[k * O + o] = (double)w[i];
    }
}

// ---------------------------------------------------------------------------
// ConvTranspose2d(k=4,s=2,p=1), fp64, LDS weight tile — PARTIAL-SUM variant
// (r10-proven) + FMA-contracted inner (4 chained += instead of 4-term sum).
// ---------------------------------------------------------------------------
template <bool RELU_A, bool ADBL>
__global__ __launch_bounds__(256) void convt_part_kernel(
    const void* __restrict__ inA_, int CA,
    const float* __restrict__ inB, int CB,
    const double* __restrict__ wp,   // [4][CIN][COUT][4] f64
    double* __restrict__ parts,      // [nSplit][B*COUT*Hout*Wout]
    int COUT, int Hin, int Win, int nSplit, int B, int TOT) {
    const int NCO = 16;
    const int CIN = CA + CB;
    const int cog = blockIdx.y >> 2;
    const int pp = blockIdx.y & 3;
    const int ry = pp >> 1, rx = pp & 1;
    const int b = blockIdx.z % B;
    const int sp = blockIdx.z / B;
    const int cinPer = CIN / nSplit;     // <= 64
    const int c0 = sp * cinPer, c1 = c0 + cinPer;
    const int co0 = cog * NCO;
    const int plane = Hin * Win;
    const int Hout = Hin * 2, Wout = Win * 2;
    double* out = parts + (size_t)sp * TOT;

    __shared__ double wl[64 * 64];       // 32 KiB max
    for (int i = threadIdx.x; i < cinPer * 64; i += 256) {
        int ci = i >> 6, k = i & 63;
        wl[i] = wp[(((size_t)pp * CIN + c0 + ci) * COUT + co0) * 4 + k];
    }
    __syncthreads();

    for (int p = blockIdx.x * 256 + threadIdx.x; p < plane; p += gridDim.x * 256) {
        int m = p / Win, n = p - m * Win;
        int iy0 = m + ry - 1, ix0 = n + rx - 1;
        int oy = 2 * m + ry, ox = 2 * n + rx;
        double f00 = (iy0 >= 0 && ix0 >= 0) ? 1.0 : 0.0;
        double f01 = (iy0 >= 0 && ix0 + 1 < Win) ? 1.0 : 0.0;
        double f10 = (iy0 + 1 < Hin && ix0 >= 0) ? 1.0 : 0.0;
        double f11 = (iy0 + 1 < Hin && ix0 + 1 < Win) ? 1.0 : 0.0;
        int cy0 = max(iy0, 0), cy1 = min(iy0 + 1, Hin - 1);
        int cx0 = max(ix0, 0), cx1 = min(ix0 + 1, Win - 1);
        int o00 = cy0 * Win + cx0, o01 = cy0 * Win + cx1;
        int o10 = cy1 * Win + cx0, o11 = cy1 * Win + cx1;

        double acc[16];
#pragma unroll
        for (int k = 0; k < 16; ++k) acc[k] = 0.0;

        int a0 = min(c0, CA), a1 = min(c1, CA);
        for (int c = a0; c < a1; ++c) {
            double x00, x01, x10, x11;
            if (ADBL) {
                const double* s = (const double*)inA_ + ((size_t)b * CA + c) * plane;
                x00 = f00 * s[o00]; x01 = f01 * s[o01];
                x10 = f10 * s[o10]; x11 = f11 * s[o11];
            } else {
                const float* s = (const float*)inA_ + ((size_t)b * CA + c) * plane;
                x00 = f00 * (double)s[o00]; x01 = f01 * (double)s[o01];
                x10 = f10 * (double)s[o10]; x11 = f11 * (double)s[o11];
            }
            if (RELU_A) {
                x00 = fmax(x00, 0.0); x01 = fmax(x01, 0.0);
                x10 = fmax(x10, 0.0); x11 = fmax(x11, 0.0);
            }
            const double2* w2 = (const double2*)&wl[(c - c0) * 64];
#pragma unroll
            for (int k = 0; k < 16; ++k) {
                double2 wa = w2[k * 2], wb = w2[k * 2 + 1];
                acc[k] += x00 * wa.x;
                acc[k] += x01 * wa.y;
                acc[k] += x10 * wb.x;
                acc[k] += x11 * wb.y;
            }
        }
        if (CB > 0 && c1 > CA) {
            int b0 = max(c0, CA) - CA, b1 = c1 - CA;
            const float* srcB = inB + (size_t)b * CB * plane;
            for (int c = b0; c < b1; ++c) {
                const float* s = srcB + (size_t)c * plane;
                double x00 = f00 * (double)s[o00], x01 = f01 * (double)s[o01];
                double x10 = f10 * (double)s[o10], x11 = f11 * (double)s[o11];
                const double2* w2 = (const double2*)&wl[(c + CA - c0) * 64];
#pragma unroll
                for (int k = 0; k < 16; ++k) {
                    double2 wa = w2[k * 2], wb = w2[k * 2 + 1];
                    acc[k] += x00 * wa.x;
                    acc[k] += x01 * wa.y;
                    acc[k] += x10 * wb.x;
                    acc[k] += x11 * wb.y;
                }
            }
        }

        size_t ob = ((size_t)b * COUT + co0) * (size_t)Hout * Wout +
                    (size_t)oy * Wout + ox;
#pragma unroll
        for (int k = 0; k < 16; ++k)
            out[ob + (size_t)k * Hout * Wout] = acc[k];
    }
}

// out[i] = bias[ch(i)] + sum_sp parts[sp][i]
__global__ void reduce_part_kernel(const double* __restrict__ parts,
                                   const float* __restrict__ bias,
                                   double* __restrict__ out,
                                   int nSplit, int COUT, int HWo, int TOT) {
    int i = blockIdx.x * blockDim.x + threadIdx.x;
    if (i < TOT) {
        double a = (double)bias[(i / HWo) % COUT];
        for (int sp = 0; sp < nSplit; ++sp) a += parts[(size_t)sp * TOT + i];
        out[i] = a;
    }
}

// ---------------------------------------------------------------------------
// 16-cout x PX-pixel register-tiled fp64 conv for L4/L5 (r11 structure):
// + FMA-contracted inner loop (4 chained +=)
// + 16 KiB LDS weight staging in 4 sub-chunks of 32 cins (same cin order)
// Grid: x = Hin*(Win/PX)/256 (exact), y = cog*4+pp, z = b.
// ---------------------------------------------------------------------------
template <int PX>
__global__ __launch_bounds__(256) void convt_reg_kernel(
    const double* __restrict__ zin, const float* __restrict__ xin,
    const double* __restrict__ wr,   // [4][NCOG][128][16][4] f64
    const float* __restrict__ bias,
    double* __restrict__ out,
    int COUT, int Hin, int Win) {
    const int NCOG = COUT >> 4;
    const int plane = Hin * Win;
    const int Wq = Win / PX;
    const int cog = blockIdx.y >> 2, pp = blockIdx.y & 3;
    const int ry = pp >> 1, rx = pp & 1;
    const int b = blockIdx.z;
    __shared__ double wl[2048];       // 32 cin x (16co x 4tap) = 16 KiB

    int t = blockIdx.x * 256 + threadIdx.x;
    int m = t / Wq, n0 = (t - m * Wq) * PX;
    int r0 = m + ry - 1, r1 = r0 + 1;
    double mr0 = (r0 >= 0) ? 1.0 : 0.0;
    double mr1 = (r1 < Hin) ? 1.0 : 0.0;
    int cr0 = max(r0, 0) * Win, cr1 = min(r1, Hin - 1) * Win;
    const int ib = rx ? 0 : 1;
    const int eidx = rx ? PX : 0;
    int eoff = rx ? min(n0 + PX, Win - 1) : max(n0 - 1, 0);
    double me = rx ? ((n0 + PX < Win) ? 1.0 : 0.0) : ((n0 > 0) ? 1.0 : 0.0);
    double me0 = me * mr0, me1 = me * mr1;

    double acc[16][PX];
#pragma unroll
    for (int k = 0; k < 16; ++k) {
        double bvv = (double)bias[cog * 16 + k];
#pragma unroll
        for (int tt = 0; tt < PX; ++tt) acc[k][tt] = bvv;
    }

    const double* wbase = wr + (size_t)(pp * NCOG + cog) * 128 * 64;

    // 4 stages of 32 cins: st 0,1 = zin (f64, relu); st 2,3 = xin (f32).
    for (int st = 0; st < 4; ++st) {
        if (st > 0) __syncthreads();
        for (int i = threadIdx.x; i < 2048; i += 256)
            wl[i] = wbase[st * 2048 + i];
        __syncthreads();
        if (st < 2) {
            const double* s = zin + ((size_t)b * 64 + st * 32) * plane;
            for (int c = 0; c < 32; ++c) {
                double xa0[PX + 1], xa1[PX + 1];
#pragma unroll
                for (int j = 0; j < PX / 2; ++j) {
                    double2 v0 = *(const double2*)(s + cr0 + n0 + 2 * j);
                    double2 v1 = *(const double2*)(s + cr1 + n0 + 2 * j);
                    xa0[ib + 2 * j] = mr0 * fmax(v0.x, 0.0);
                    xa0[ib + 2 * j + 1] = mr0 * fmax(v0.y, 0.0);
                    xa1[ib + 2 * j] = mr1 * fmax(v1.x, 0.0);
                    xa1[ib + 2 * j + 1] = mr1 * fmax(v1.y, 0.0);
                }
                xa0[eidx] = me0 * fmax(s[cr0 + eoff], 0.0);
                xa1[eidx] = me1 * fmax(s[cr1 + eoff], 0.0);
                const double2* w2 = (const double2*)&wl[c * 64];
#pragma unroll
                for (int co = 0; co < 16; ++co) {
                    double2 wa = w2[co * 2], wb = w2[co * 2 + 1];
#pragma unroll
                    for (int tt = 0; tt < PX; ++tt) {
                        acc[co][tt] += wa.x * xa0[tt];
                        acc[co][tt] += wa.y * xa0[tt + 1];
                        acc[co][tt] += wb.x * xa1[tt];
                        acc[co][tt] += wb.y * xa1[tt + 1];
                    }
                }
                s += plane;
            }
        } else {
            const float* s = xin + ((size_t)b * 64 + (st - 2) * 32) * plane;
            for (int c = 0; c < 32; ++c) {
                double xa0[PX + 1], xa1[PX + 1];
#pragma unroll
                for (int j = 0; j < PX / 2; ++j) {
                    float2 v0 = *(const float2*)(s + cr0 + n0 + 2 * j);
                    float2 v1 = *(const float2*)(s + cr1 + n0 + 2 * j);
                    xa0[ib + 2 * j] = mr0 * (double)v0.x;
                    xa0[ib + 2 * j + 1] = mr0 * (double)v0.y;
                    xa1[ib + 2 * j] = mr1 * (double)v1.x;
                    xa1[ib + 2 * j + 1] = mr1 * (double)v1.y;
                }
                xa0[eidx] = me0 * (double)s[cr0 + eoff];
                xa1[eidx] = me1 * (double)s[cr1 + eoff];
                const double2* w2 = (const double2*)&wl[c * 64];
#pragma unroll
                for (int co = 0; co < 16; ++co) {
                    double2 wa = w2[co * 2], wb = w2[co * 2 + 1];
#pragma unroll
                    for (int tt = 0; tt < PX; ++tt) {
                        acc[co][tt] += wa.x * xa0[tt];
                        acc[co][tt] += wa.y * xa0[tt + 1];
                        acc[co][tt] += wb.x * xa1[tt];
                        acc[co][tt] += wb.y * xa1[tt + 1];
                    }
                }
                s += plane;
            }
        }
    }

    int oy = 2 * m + ry;
    size_t ob = (size_t)(b * COUT + cog * 16) * plane * 4 + (size_t)oy * (Win * 2);
#pragma unroll
    for (int co = 0; co < 16; ++co)
#pragma unroll
        for (int tt = 0; tt < PX; ++tt)
            out[ob + (size_t)co * plane * 4 + 2 * (n0 + tt) + rx] = acc[co][tt];
}

// ---------------------------------------------------------------------------
// Fused heads (fp64) — r7-proven (LDS weight staging, broadcast double2).
// ---------------------------------------------------------------------------
__global__ __launch_bounds__(256) void head_lds_kernel(
    const double* __restrict__ z5,
    const double* __restrict__ wvT,  // [64][66] f64
    const float* __restrict__ bv,
    const double* __restrict__ wcT,  // [64][22] f64
    const float* __restrict__ bc,
    float* __restrict__ vert, double* __restrict__ dirs,
    float* __restrict__ label) {
    int p = blockIdx.x * 256 + threadIdx.x;
    int half = blockIdx.y;
    int b = blockIdx.z;
    __shared__ double wl[64 * 44];   // 22.5 KiB
    if (half == 0) {
        for (int i = threadIdx.x; i < 64 * 44; i += 256) {
            int c = i / 44, k = i - c * 44;
            wl[i] = wvT[c * 66 + k];
        }
    } else {
        for (int i = threadIdx.x; i < 64 * 44; i += 256) {
            int c = i / 44, k = i - c * 44;
            wl[i] = (k < 22) ? wvT[c * 66 + 44 + k] : wcT[c * 22 + (k - 22)];
        }
    }
    __syncthreads();

    const double* xp = z5 + (size_t)b * 64 * HW_IMG + p;
    if (half == 0) {
        double acc[44];
#pragma unroll
        for (int k = 0; k < 44; ++k) acc[k] = (double)bv[k];
        for (int c = 0; c < 64; ++c) {
            double x = fmax(xp[(size_t)c * HW_IMG], 0.0);
            const double2* w2 = (const double2*)&wl[c * 44];
#pragma unroll
            for (int j = 0; j < 22; ++j) {
                double2 w = w2[j];
                acc[2 * j] += x * w.x; acc[2 * j + 1] += x * w.y;
            }
        }
        float* op = vert + (size_t)b * 66 * HW_IMG + p;
#pragma unroll
        for (int k = 0; k < 44; ++k) op[(size_t)k * HW_IMG] = (float)acc[k];
        dirs[(size_t)b * 2 * HW_IMG + p] = acc[0];
        dirs[(size_t)b * 2 * HW_IMG + HW_IMG + p] = acc[1];
    } else {
        double acc[22], lg[22];
#pragma unroll
        for (int k = 0; k < 22; ++k) { acc[k] = (double)bv[44 + k]; lg[k] = (double)bc[k]; }
        for (int c = 0; c < 64; ++c) {
            double x = fmax(xp[(size_t)c * HW_IMG], 0.0);
            const double2* w2 = (const double2*)&wl[c * 44];
#pragma unroll
            for (int j = 0; j < 11; ++j) {
                double2 w = w2[j];
                acc[2 * j] += x * w.x; acc[2 * j + 1] += x * w.y;
            }
#pragma unroll
            for (int j = 0; j < 11; ++j) {
                double2 w = w2[11 + j];
                lg[2 * j] += x * w.x; lg[2 * j + 1] += x * w.y;
            }
        }
        float* op = vert + ((size_t)b * 66 + 44) * HW_IMG + p;
#pragma unroll
        for (int k = 0; k < 22; ++k) op[(size_t)k * HW_IMG] = (float)acc[k];
        int bi = 0; double bvv = lg[0];
#pragma unroll
        for (int k = 1; k < 22; ++k)
            if (lg[k] > bvv) { bvv = lg[k]; bi = k; }   // first max, like np.argmax
        label[(size_t)b * HW_IMG + p] = (float)bi;
    }
}

// ---------------------------------------------------------------------------
// Vote prepass (r12-proven): seg-fuse, depth/mask sums, ray params.
// ---------------------------------------------------------------------------
__global__ __launch_bounds__(256) void vote_prep_kernel(
    const float* __restrict__ seg, const float* __restrict__ depth,
    const double* __restrict__ dirs,
    double* __restrict__ rayS, double* __restrict__ rayU,
    double* __restrict__ rayV, double* __restrict__ rayRU,
    double* __restrict__ rayRV, double* __restrict__ rayN,
    double* __restrict__ sums) {
    int p = blockIdx.x * 256 + threadIdx.x;
    int b = blockIdx.z;
    double s = 0.0;
    const float* sp = seg + (size_t)b * NCLS * HW_IMG + p;
    for (int c = 0; c < NCLS; ++c) s += (double)sp[(size_t)c * HW_IMG];
    s = fmin(fmax(s, 0.0), 1.0);
    bool msk = s > 0.5;
    double d = (double)depth[(size_t)b * HW_IMG + p];
    double dm = msk ? d : 0.0;
    double mm = msk ? 1.0 : 0.0;
    for (int off = 32; off > 0; off >>= 1) {
        dm += __shfl_down(dm, off);
        mm += __shfl_down(mm, off);
    }
    __shared__ double sdm[4], smm[4];
    int wid = threadIdx.x >> 6, lane = threadIdx.x & 63;
    if (lane == 0) { sdm[wid] = dm; smm[wid] = mm; }
    __syncthreads();
    if (threadIdx.x == 0) {
        atomicAdd(&sums[b * 2 + 0], sdm[0] + sdm[1] + sdm[2] + sdm[3]);
        atomicAdd(&sums[b * 2 + 1], smm[0] + smm[1] + smm[2] + smm[3]);
    }
    size_t idx = (size_t)b * HW_IMG + p;
    if (msk) {
        double dx = dirs[(size_t)b * 2 * HW_IMG + p];
        double dy = dirs[(size_t)b * 2 * HW_IMG + HW_IMG + p];
        double nrm = sqrt(dx * dx + dy * dy) + 1e-6;
        double u = dx / nrm, v = dy / nrm;
        double xf = (double)(p % W_IMG), yf = (double)(p / W_IMG);
        double tmax = 1e30;
        if (u > 1e-9)       tmax = fmin(tmax, ((double)W_IMG - 0.25 - xf) / u);
        else if (u < -1e-9) tmax = fmin(tmax, (-0.75 - xf) / u);
        if (v > 1e-9)       tmax = fmin(tmax, ((double)H_IMG - 0.25 - yf) / v);
        else if (v < -1e-9) tmax = fmin(tmax, (-0.75 - yf) / v);
        int nst = VOTE_STEPS;
        if (tmax < (double)VOTE_STEPS) nst = (int)tmax + 1;
        rayS[idx] = s;
        rayU[idx] = u;
        rayV[idx] = v;
        rayRU[idx] = (u != 0.0) ? 1.0 / u : 0.0;
        rayRV[idx] = (v != 0.0) ? 1.0 / v : 0.0;
        rayN[idx] = (double)nst;
    } else {
        rayS[idx] = 0.0;
    }
}

// ---------------------------------------------------------------------------
// Vote tile pass (r12-proven): one 64x64 tile x one ray chunk per block;
// LDS f64 atomics; exact rint check inside conservative t-interval.
// ---------------------------------------------------------------------------
__global__ __launch_bounds__(256) void vote_tile_kernel(
    const double* __restrict__ rayS, const double* __restrict__ rayU,
    const double* __restrict__ rayV, const double* __restrict__ rayRU,
    const double* __restrict__ rayRV, const double* __restrict__ rayN,
    double* __restrict__ vparts) {
    int chunk = blockIdx.x;
    int tile = blockIdx.y;
    int b = blockIdx.z;
    int tx0 = (tile % NTX) * TW, ty0 = (tile / NTX) * TH;
    __shared__ double vt[TW * TH];   // 32 KiB
    for (int i = threadIdx.x; i < TW * TH; i += 256) vt[i] = 0.0;
    __syncthreads();

    size_t base = (size_t)b * HW_IMG;
    int p0 = chunk * CHPIX;
    for (int q = threadIdx.x; q < CHPIX; q += 256) {
        int p = p0 + q;
        double s = rayS[base + p];
        if (s == 0.0) continue;
        double u = rayU[base + p], v = rayV[base + p];
        double ru = rayRU[base + p], rv = rayRV[base + p];
        int nst = (int)rayN[base + p];
        double xf = (double)(p % W_IMG), yf = (double)(p / W_IMG);
        double ta = 1.0, tb = (double)nst;
        if (ru != 0.0) {
            double lo = ((double)(tx0 - 1) - xf) * ru;
            double hi = ((double)(tx0 + TW) - xf) * ru;
            ta = fmax(ta, fmin(lo, hi));
            tb = fmin(tb, fmax(lo, hi));
        } else {
            if (xf < (double)(tx0 - 1) || xf > (double)(tx0 + TW)) continue;
        }
        if (rv != 0.0) {
            double lo = ((double)(ty0 - 1) - yf) * rv;
            double hi = ((double)(ty0 + TH) - yf) * rv;
            ta = fmax(ta, fmin(lo, hi));
            tb = fmin(tb, fmax(lo, hi));
        } else {
            if (yf < (double)(ty0 - 1) || yf > (double)(ty0 + TH)) continue;
        }
        if (ta > tb) continue;
        int t0 = (int)ceil(ta), t1 = (int)floor(tb);
        for (int t = t0; t <= t1; ++t) {
            double tf = (double)t;
            int xi = (int)rint(xf + tf * u);   // half-to-even, like np.round
            int yi = (int)rint(yf + tf * v);
            if (xi >= tx0 && xi < tx0 + TW && yi >= ty0 && yi < ty0 + TH)
                atomicAdd(&vt[(yi - ty0) * TW + (xi - tx0)], s);
        }
    }
    __syncthreads();
    double* dst = vparts + (((size_t)chunk * 4 + b) * NTILE + tile) * (TW * TH);
    for (int i = threadIdx.x; i < TW * TH; i += 256) dst[i] = vt[i];
}

// voteacc[b][cell] = sum over chunks (fixed order) of tile partials
__global__ void vote_reduce_kernel(const double* __restrict__ vparts,
                                   double* __restrict__ voteacc,
                                   float* __restrict__ vote) {
    int i = blockIdx.x * 256 + threadIdx.x;
    if (i < 4 * HW_IMG) {
        int b = i / HW_IMG, cell = i - b * HW_IMG;
        int y = cell / W_IMG, x = cell - y * W_IMG;
        int tile = (y / TH) * NTX + (x / TW);
        int ci = (y % TH) * TW + (x % TW);
        double a = 0.0;
        for (int c = 0; c < NCHUNK; ++c)
            a += vparts[(((size_t)c * 4 + b) * NTILE + tile) * (TW * TH) + ci];
        voteacc[i] = a;
        vote[i] = (float)a;
    }
}

__global__ __launch_bounds__(1024) void center_d_kernel(
    const double* __restrict__ voteacc, const double* __restrict__ sums,
    const float* __restrict__ fx, const float* __restrict__ fy,
    const float* __restrict__ px, const float* __restrict__ py,
    float* __restrict__ centers, float* __restrict__ transl) {
    int b = blockIdx.x;
    const double* vb = voteacc + (size_t)b * HW_IMG;
    double best = -1.0;
    int bi = HW_IMG;
    for (int i = threadIdx.x; i < HW_IMG; i += 1024) {
        double v = vb[i];
        if (v > best || (v == best && i < bi)) { best = v; bi = i; }
    }
    for (int off = 32; off > 0; off >>= 1) {
        double ov = __shfl_down(best, off);
        int oi = __shfl_down(bi, off);
        if (ov > best || (ov == best && oi < bi)) { best = ov; bi = oi; }
    }
    __shared__ double sbv[16];
    __shared__ int sbi[16];
    int wid = threadIdx.x >> 6, lane = threadIdx.x & 63;
    if (lane == 0) { sbv[wid] = best; sbi[wid] = bi; }
    __syncthreads();
    if (threadIdx.x == 0) {
        for (int q = 1; q < 16; ++q)
            if (sbv[q] > best || (sbv[q] == best && sbi[q] < bi)) {
                best = sbv[q]; bi = sbi[q];
            }
        double cx = (double)(bi % W_IMG), cy = (double)(bi / W_IMG);
        double tz = sums[b * 2 + 0] / (sums[b * 2 + 1] + 1e-6);
        double tx = (cx - (double)px[0]) * tz / (double)fx[0];
        double ty = (cy - (double)py[0]) * tz / (double)fy[0];
        centers[b * 2 + 0] = (float)cx;
        centers[b * 2 + 1] = (float)cy;
        transl[b * 3 + 0] = (float)tx;
        transl[b * 3 + 1] = (float)ty;
        transl[b * 3 + 2] = (float)tz;
    }
}

// ---------------------------------------------------------------------------
extern "C" void kernel_launch(void* const* d_in, const int* in_sizes, int n_in,
                              void* d_out, int out_size, void* d_ws, size_t ws_size,
                              hipStream_t stream) {
    const float* x1 = (const float*)d_in[0];
    const float* x2 = (const float*)d_in[1];
    const float* x3 = (const float*)d_in[2];
    const float* x4 = (const float*)d_in[3];
    const float* x5 = (const float*)d_in[4];
    const float* depth = (const float*)d_in[5];
    const float* seg = (const float*)d_in[6];
    const float* fx = (const float*)d_in[7];
    const float* fy = (const float*)d_in[8];
    const float* px = (const float*)d_in[9];
    const float* py = (const float*)d_in[10];
    const float* w5 = (const float*)d_in[11];
    const float* b5 = (const float*)d_in[12];
    const float* w4 = (const float*)d_in[13];
    const float* b4 = (const float*)d_in[14];
    const float* w3 = (const float*)d_in[15];
    const float* b3 = (const float*)d_in[16];
    const float* w2 = (const float*)d_in[17];
    const float* b2 = (const float*)d_in[18];
    const float* w1 = (const float*)d_in[19];
    const float* b1 = (const float*)d_in[20];
    const float* wv = (const float*)d_in[21];
    const float* bv = (const float*)d_in[22];
    const float* wc = (const float*)d_in[23];
    const float* bc = (const float*)d_in[24];

    // output layout (flat f32, reference return order)
    float* out = (float*)d_out;
    float* vert = out;                               // [4,66,256,320]
    float* label = vert + (size_t)4 * 66 * HW_IMG;   // [4,256,320]
    float* vote = label + (size_t)4 * HW_IMG;        // [4,256,320]
    float* centers = vote + (size_t)4 * HW_IMG;      // [4,2]
    float* transl = centers + 8;                     // [4,3]

    // workspace layout (all f64) — identical extent to r7/r12 (proven).
    double* zA = (double*)d_ws;            // 20,971,520
    double* zB = zA + 20971520;            //  5,242,880
    double* dirs = zB + 5242880;           //    655,360
    double* voteacc = dirs + 655360;       //    327,680
    double* sums = voteacc + 327680;       //          8
    double* wp5 = sums + 8;                // 2,097,152  [4][512][256][4]
    double* wp4 = wp5 + 2097152;           // 1,048,576  [4][512][128][4]
    double* wp3 = wp4 + 1048576;           //   262,144  [4][256][64][4]
    double* wr2 = wp3 + 262144;            //   131,072  [4][4][128][16][4]
    double* wr1 = wr2 + 131072;            //   131,072  [4][4][128][16][4]
    double* wvT = wr1 + 131072;            //     4,224
    double* wcT = wvT + 4224;              //     1,408
    double* z1 = zA; double* z2 = zB; double* z3 = zA; double* z4 = zB; double* z5 = zA;
    // conv partial-sum scratch (r10-proven): dead zA interior [2M, 7.25M)
    double* parts = zA + 2000000;
    // ray arrays: zB is dead after L5 (z4 consumed)
    double* rayS = zB;                     // 327,680 each
    double* rayU = zB + 327680;
    double* rayV = zB + 2 * 327680;
    double* rayRU = zB + 3 * 327680;
    double* rayRV = zB + 4 * 327680;
    double* rayN = zB + 5 * 327680;        // total 1.97M <= 5.24M ok
    // vote tile partials: zA (z5) is dead after heads; 16*4*20*4096 = 5.24M
    double* vparts = zA;

    hipMemsetAsync(sums, 0, 8 * sizeof(double), stream);

    // weight repacks
    auto rp = [&](const float* w, double* wp, int CIN, int COUT) {
        int total = CIN * COUT * 16;
        repack_kernel<<<(total + 255) / 256, 256, 0, stream>>>(w, wp, CIN, COUT);
    };
    rp(w5, wp5, 512, 256);
    rp(w4, wp4, 512, 128);
    rp(w3, wp3, 256, 64);
    repackR_kernel<<<(131072 + 255) / 256, 256, 0, stream>>>(w2, wr2, 128, 64);
    repackR_kernel<<<(131072 + 255) / 256, 256, 0, stream>>>(w1, wr1, 128, 64);
    transpose_d_kernel<<<(66 * 64 + 255) / 256, 256, 0, stream>>>(wv, wvT, 66, 64);
    transpose_d_kernel<<<(22 * 64 + 255) / 256, 256, 0, stream>>>(wc, wcT, 22, 64);

    // L1: x1[4,512,8,10] -> z1[4,256,16,20], split 8, partial+reduce
    convt_part_kernel<false, false><<<dim3(1, 64, 32), 256, 0, stream>>>(
        x1, 512, nullptr, 0, wp5, parts, 256, 8, 10, 8, 4, 327680);
    reduce_part_kernel<<<1280, 256, 0, stream>>>(parts, b5, z1, 8, 256, 320, 327680);
    // L2: [relu(z1)|x2] -> z2[4,128,32,40], split 8, partial+reduce
    convt_part_kernel<true, true><<<dim3(2, 32, 32), 256, 0, stream>>>(
        z1, 256, x2, 256, wp4, parts, 128, 16, 20, 8, 4, 655360);
    reduce_part_kernel<<<2560, 256, 0, stream>>>(parts, b4, z2, 8, 128, 1280, 655360);
    // L3: [relu(z2)|x3] -> z3[4,64,64,80], split 4, partial+reduce
    convt_part_kernel<true, true><<<dim3(5, 16, 16), 256, 0, stream>>>(
        z2, 128, x3, 128, wp3, parts, 64, 32, 40, 4, 4, 1310720);
    reduce_part_kernel<<<5120, 256, 0, stream>>>(parts, b3, z3, 4, 64, 5120, 1310720);
    // L4: [relu(z3)|x4] -> z4[4,64,128,160]  (16co x 2px tile, 16 KiB LDS)
    convt_reg_kernel<2><<<dim3(10, 16, 4), 256, 0, stream>>>(
        z3, x4, wr2, b2, z4, 64, 64, 80);
    // L5: [relu(z4)|x5] -> z5[4,64,256,320]  (16co x 2px tile, 16 KiB LDS)
    convt_reg_kernel<2><<<dim3(40, 16, 4), 256, 0, stream>>>(
        z4, x5, wr1, b1, z5, 64, 128, 160);

    // fused heads (r7-proven)
    head_lds_kernel<<<dim3(320, 2, 4), 256, 0, stream>>>(z5, wvT, bv, wcT, bc,
                                                         vert, dirs, label);

    // hough voting: prepass -> LDS-tiled accumulate -> reduce -> center
    vote_prep_kernel<<<dim3(320, 1, 4), 256, 0, stream>>>(
        seg, depth, dirs, rayS, rayU, rayV, rayRU, rayRV, rayN, sums);
    vote_tile_kernel<<<dim3(NCHUNK, NTILE, 4), 256, 0, stream>>>(
        rayS, rayU, rayV, rayRU, rayRV, rayN, vparts);
    vote_reduce_kernel<<<(4 * HW_IMG + 255) / 256, 256, 0, stream>>>(
        vparts, voteacc, vote);
    center_d_kernel<<<4, 1024, 0, stream>>>(voteacc, sums, fx, fy, px, py,
                                            centers, transl);
}

// Round 14
// 1941.518 us; speedup vs baseline: 1.1076x; 1.1076x over previous
//
#include <hip/hip_runtime.h>
#include <cstdint>
#include <cstddef>

#define H_IMG 256
#define W_IMG 320
#define HW_IMG (H_IMG * W_IMG)   // 81920
#define NCLS 22
#define VOTE_STEPS 160
#define TW 64
#define TH 64
#define NTX 5
#define NTY 4
#define NTILE (NTX * NTY)        // 20
#define NCHUNK 16
#define CHPIX (HW_IMG / NCHUNK)  // 5120

// ---------------------------------------------------------------------------
// Weight repack (r3-proven): w[cin][cout][4][4] f32 -> wp[pp][cin][cout][4] f64
// ---------------------------------------------------------------------------
__global__ void repack_kernel(const float* __restrict__ w, double* __restrict__ wp,
                              int CIN, int COUT) {
    int total = CIN * COUT * 16;
    for (int i = blockIdx.x * blockDim.x + threadIdx.x; i < total;
         i += gridDim.x * blockDim.x) {
        int j = i & 3;
        int co = (i >> 2) % COUT;
        int rest = (i >> 2) / COUT;   // pp*CIN + cin
        int cin = rest % CIN;
        int pp = rest / CIN;
        int ry = pp >> 1, rx = pp & 1;
        int dy = j >> 1, dx = j & 1;
        int ky = 3 - ry - 2 * dy;
        int kx = 3 - rx - 2 * dx;
        wp[i] = (double)w[((size_t)cin * COUT + co) * 16 + ky * 4 + kx];
    }
}

// Repack for the 16-cout register-tiled conv: wr[pp][cog][cin][co(16)][tap(4)]
__global__ void repackR_kernel(const float* __restrict__ w, double* __restrict__ wr,
                               int CIN, int COUT) {
    int NCOG = COUT >> 4;
    int total = CIN * COUT * 16;
    for (int i = blockIdx.x * blockDim.x + threadIdx.x; i < total;
         i += gridDim.x * blockDim.x) {
        int tap = i & 3;
        int co = (i >> 2) & 15;
        int rest = i >> 6;            // (pp*NCOG+cog)*CIN + cin
        int cin = rest % CIN;
        int pc = rest / CIN;
        int cog = pc % NCOG;
        int pp = pc / NCOG;
        int ry = pp >> 1, rx = pp & 1;
        int dy = tap >> 1, dxx = tap & 1;
        int ky = 3 - ry - 2 * dy;
        int kx = 3 - rx - 2 * dxx;
        wr[i] = (double)w[((size_t)cin * COUT + (cog * 16 + co)) * 16 + ky * 4 + kx];
    }
}

// w[O][K] f32 -> wt[K][O] f64
__global__ void transpose_d_kernel(const float* __restrict__ w, double* __restrict__ wt,
                                   int O, int K) {
    int i = blockIdx.x * blockDim.x + threadIdx.x;
    if (i < O * K) {
        int o = i / K, k = i - o * K;
        wt[k * O + o] = (double)w[i];
    }
}

// ---------------------------------------------------------------------------
// ConvTranspose2d(k=4,s=2,p=1), fp64, LDS weight tile — PARTIAL-SUM variant
// (r12-proven form: 4-term sum inner, blockDim-parameterized stride).
// ---------------------------------------------------------------------------
template <bool RELU_A, bool ADBL>
__global__ __launch_bounds__(320) void convt_part_kernel(
    const void* __restrict__ inA_, int CA,
    const float* __restrict__ inB, int CB,
    const double* __restrict__ wp,   // [4][CIN][COUT][4] f64
    double* __restrict__ parts,      // [nSplit][B*COUT*Hout*Wout]
    int COUT, int Hin, int Win, int nSplit, int B, int TOT) {
    const int NCO = 16;
    const int CIN = CA + CB;
    const int cog = blockIdx.y >> 2;
    const int pp = blockIdx.y & 3;
    const int ry = pp >> 1, rx = pp & 1;
    const int b = blockIdx.z % B;
    const int sp = blockIdx.z / B;
    const int cinPer = CIN / nSplit;     // <= 64
    const int c0 = sp * cinPer, c1 = c0 + cinPer;
    const int co0 = cog * NCO;
    const int plane = Hin * Win;
    const int Hout = Hin * 2, Wout = Win * 2;
    const int bs = blockDim.x;
    double* out = parts + (size_t)sp * TOT;

    __shared__ double wl[64 * 64];       // 32 KiB max
    for (int i = threadIdx.x; i < cinPer * 64; i += bs) {
        int ci = i >> 6, k = i & 63;
        wl[i] = wp[(((size_t)pp * CIN + c0 + ci) * COUT + co0) * 4 + k];
    }
    __syncthreads();

    for (int p = blockIdx.x * bs + threadIdx.x; p < plane; p += gridDim.x * bs) {
        int m = p / Win, n = p - m * Win;
        int iy0 = m + ry - 1, ix0 = n + rx - 1;
        int oy = 2 * m + ry, ox = 2 * n + rx;
        double f00 = (iy0 >= 0 && ix0 >= 0) ? 1.0 : 0.0;
        double f01 = (iy0 >= 0 && ix0 + 1 < Win) ? 1.0 : 0.0;
        double f10 = (iy0 + 1 < Hin && ix0 >= 0) ? 1.0 : 0.0;
        double f11 = (iy0 + 1 < Hin && ix0 + 1 < Win) ? 1.0 : 0.0;
        int cy0 = max(iy0, 0), cy1 = min(iy0 + 1, Hin - 1);
        int cx0 = max(ix0, 0), cx1 = min(ix0 + 1, Win - 1);
        int o00 = cy0 * Win + cx0, o01 = cy0 * Win + cx1;
        int o10 = cy1 * Win + cx0, o11 = cy1 * Win + cx1;

        double acc[16];
#pragma unroll
        for (int k = 0; k < 16; ++k) acc[k] = 0.0;

        int a0 = min(c0, CA), a1 = min(c1, CA);
        for (int c = a0; c < a1; ++c) {
            double x00, x01, x10, x11;
            if (ADBL) {
                const double* s = (const double*)inA_ + ((size_t)b * CA + c) * plane;
                x00 = f00 * s[o00]; x01 = f01 * s[o01];
                x10 = f10 * s[o10]; x11 = f11 * s[o11];
            } else {
                const float* s = (const float*)inA_ + ((size_t)b * CA + c) * plane;
                x00 = f00 * (double)s[o00]; x01 = f01 * (double)s[o01];
                x10 = f10 * (double)s[o10]; x11 = f11 * (double)s[o11];
            }
            if (RELU_A) {
                x00 = fmax(x00, 0.0); x01 = fmax(x01, 0.0);
                x10 = fmax(x10, 0.0); x11 = fmax(x11, 0.0);
            }
            const double2* w2 = (const double2*)&wl[(c - c0) * 64];
#pragma unroll
            for (int k = 0; k < 16; ++k) {
                double2 wa = w2[k * 2], wb = w2[k * 2 + 1];
                acc[k] += x00 * wa.x + x01 * wa.y + x10 * wb.x + x11 * wb.y;
            }
        }
        if (CB > 0 && c1 > CA) {
            int b0 = max(c0, CA) - CA, b1 = c1 - CA;
            const float* srcB = inB + (size_t)b * CB * plane;
            for (int c = b0; c < b1; ++c) {
                const float* s = srcB + (size_t)c * plane;
                double x00 = f00 * (double)s[o00], x01 = f01 * (double)s[o01];
                double x10 = f10 * (double)s[o10], x11 = f11 * (double)s[o11];
                const double2* w2 = (const double2*)&wl[(c + CA - c0) * 64];
#pragma unroll
                for (int k = 0; k < 16; ++k) {
                    double2 wa = w2[k * 2], wb = w2[k * 2 + 1];
                    acc[k] += x00 * wa.x + x01 * wa.y + x10 * wb.x + x11 * wb.y;
                }
            }
        }

        size_t ob = ((size_t)b * COUT + co0) * (size_t)Hout * Wout +
                    (size_t)oy * Wout + ox;
#pragma unroll
        for (int k = 0; k < 16; ++k)
            out[ob + (size_t)k * Hout * Wout] = acc[k];
    }
}

// ---------------------------------------------------------------------------
// L1-only merged-parity variant: plane = 80 (8x10), block = 320 threads
// mapping pp = tid/80, p = tid%80 (100% lane use vs 31%).  All 4 parities'
// weight slices staged (4 x 32cin x 64 = 64 KiB).  cinPer = 32 (nSplit 16).
// Grid: (1, NCOG, nSplit*B).  Math per (pp,p) identical to convt_part.
// ---------------------------------------------------------------------------
__global__ __launch_bounds__(320) void convt_part_l1_kernel(
    const float* __restrict__ xin, int CIN,     // 512
    const double* __restrict__ wp,              // [4][CIN][COUT][4] f64
    double* __restrict__ parts,                 // [16][B*COUT*32*20]
    int COUT, int nSplit, int B, int TOT) {
    const int Hin = 8, Win = 10, plane = 80;
    const int Hout = 16, Wout = 20;
    const int cog = blockIdx.y;
    const int b = blockIdx.z % B;
    const int sp = blockIdx.z / B;
    const int cinPer = CIN / nSplit;            // 32
    const int c0 = sp * cinPer;
    const int co0 = cog * 16;
    const int pp = threadIdx.x / plane;         // 0..3
    const int p = threadIdx.x - pp * plane;
    const int ry = pp >> 1, rx = pp & 1;
    double* out = parts + (size_t)sp * TOT;

    __shared__ double wl[4 * 32 * 64];          // 64 KiB
    for (int i = threadIdx.x; i < 4 * cinPer * 64; i += 320) {
        int k = i & 63;
        int ci = (i >> 6) % cinPer;
        int pq = (i >> 6) / cinPer;
        wl[i] = wp[(((size_t)pq * CIN + c0 + ci) * COUT + co0) * 4 + k];
    }
    __syncthreads();

    int m = p / Win, n = p - m * Win;
    int iy0 = m + ry - 1, ix0 = n + rx - 1;
    int oy = 2 * m + ry, ox = 2 * n + rx;
    double f00 = (iy0 >= 0 && ix0 >= 0) ? 1.0 : 0.0;
    double f01 = (iy0 >= 0 && ix0 + 1 < Win) ? 1.0 : 0.0;
    double f10 = (iy0 + 1 < Hin && ix0 >= 0) ? 1.0 : 0.0;
    double f11 = (iy0 + 1 < Hin && ix0 + 1 < Win) ? 1.0 : 0.0;
    int cy0 = max(iy0, 0), cy1 = min(iy0 + 1, Hin - 1);
    int cx0 = max(ix0, 0), cx1 = min(ix0 + 1, Win - 1);
    int o00 = cy0 * Win + cx0, o01 = cy0 * Win + cx1;
    int o10 = cy1 * Win + cx0, o11 = cy1 * Win + cx1;

    double acc[16];
#pragma unroll
    for (int k = 0; k < 16; ++k) acc[k] = 0.0;

    const float* s = xin + ((size_t)b * CIN + c0) * plane;
    const double* wpp = &wl[pp * cinPer * 64];
    for (int c = 0; c < cinPer; ++c) {
        double x00 = f00 * (double)s[o00], x01 = f01 * (double)s[o01];
        double x10 = f10 * (double)s[o10], x11 = f11 * (double)s[o11];
        const double2* w2 = (const double2*)&wpp[c * 64];
#pragma unroll
        for (int k = 0; k < 16; ++k) {
            double2 wa = w2[k * 2], wb = w2[k * 2 + 1];
            acc[k] += x00 * wa.x + x01 * wa.y + x10 * wb.x + x11 * wb.y;
        }
        s += plane;
    }

    size_t ob = ((size_t)b * COUT + co0) * (size_t)Hout * Wout +
                (size_t)oy * Wout + ox;
#pragma unroll
    for (int k = 0; k < 16; ++k)
        out[ob + (size_t)k * Hout * Wout] = acc[k];
}

// out[i] = bias[ch(i)] + sum_sp parts[sp][i]
__global__ void reduce_part_kernel(const double* __restrict__ parts,
                                   const float* __restrict__ bias,
                                   double* __restrict__ out,
                                   int nSplit, int COUT, int HWo, int TOT) {
    int i = blockIdx.x * blockDim.x + threadIdx.x;
    if (i < TOT) {
        double a = (double)bias[(i / HWo) % COUT];
        for (int sp = 0; sp < nSplit; ++sp) a += parts[(size_t)sp * TOT + i];
        out[i] = a;
    }
}

// ---------------------------------------------------------------------------
// 16-cout x PX-pixel register-tiled fp64 conv for L4/L5 (r12-proven EXACTLY:
// 32 KiB single-stage weight staging, 4-term-sum inner).
// ---------------------------------------------------------------------------
template <int PX>
__global__ __launch_bounds__(256) void convt_reg_kernel(
    const double* __restrict__ zin, const float* __restrict__ xin,
    const double* __restrict__ wr,   // [4][NCOG][128][16][4] f64
    const float* __restrict__ bias,
    double* __restrict__ out,
    int COUT, int Hin, int Win) {
    const int NCOG = COUT >> 4;
    const int plane = Hin * Win;
    const int Wq = Win / PX;
    const int cog = blockIdx.y >> 2, pp = blockIdx.y & 3;
    const int ry = pp >> 1, rx = pp & 1;
    const int b = blockIdx.z;
    __shared__ double wl[4096];       // 64 cin x (16co x 4tap) = 32 KiB

    int t = blockIdx.x * 256 + threadIdx.x;
    int m = t / Wq, n0 = (t - m * Wq) * PX;
    int r0 = m + ry - 1, r1 = r0 + 1;
    double mr0 = (r0 >= 0) ? 1.0 : 0.0;
    double mr1 = (r1 < Hin) ? 1.0 : 0.0;
    int cr0 = max(r0, 0) * Win, cr1 = min(r1, Hin - 1) * Win;
    const int ib = rx ? 0 : 1;
    const int eidx = rx ? PX : 0;
    int eoff = rx ? min(n0 + PX, Win - 1) : max(n0 - 1, 0);
    double me = rx ? ((n0 + PX < Win) ? 1.0 : 0.0) : ((n0 > 0) ? 1.0 : 0.0);
    double me0 = me * mr0, me1 = me * mr1;

    double acc[16][PX];
#pragma unroll
    for (int k = 0; k < 16; ++k) {
        double bvv = (double)bias[cog * 16 + k];
#pragma unroll
        for (int tt = 0; tt < PX; ++tt) acc[k][tt] = bvv;
    }

    const double* wbase = wr + (size_t)(pp * NCOG + cog) * 128 * 64;

    // ---- chunk 0: cin 0..63 from zin (f64, relu) ----
    for (int i = threadIdx.x; i < 4096; i += 256) wl[i] = wbase[i];
    __syncthreads();
    {
        const double* s = zin + (size_t)b * 64 * plane;
        for (int c = 0; c < 64; ++c) {
            double xa0[PX + 1], xa1[PX + 1];
#pragma unroll
            for (int j = 0; j < PX / 2; ++j) {
                double2 v0 = *(const double2*)(s + cr0 + n0 + 2 * j);
                double2 v1 = *(const double2*)(s + cr1 + n0 + 2 * j);
                xa0[ib + 2 * j] = mr0 * fmax(v0.x, 0.0);
                xa0[ib + 2 * j + 1] = mr0 * fmax(v0.y, 0.0);
                xa1[ib + 2 * j] = mr1 * fmax(v1.x, 0.0);
                xa1[ib + 2 * j + 1] = mr1 * fmax(v1.y, 0.0);
            }
            xa0[eidx] = me0 * fmax(s[cr0 + eoff], 0.0);
            xa1[eidx] = me1 * fmax(s[cr1 + eoff], 0.0);
            const double2* w2 = (const double2*)&wl[c * 64];
#pragma unroll
            for (int co = 0; co < 16; ++co) {
                double2 wa = w2[co * 2], wb = w2[co * 2 + 1];
#pragma unroll
                for (int tt = 0; tt < PX; ++tt)
                    acc[co][tt] += wa.x * xa0[tt] + wa.y * xa0[tt + 1] +
                                   wb.x * xa1[tt] + wb.y * xa1[tt + 1];
            }
            s += plane;
        }
    }
    __syncthreads();
    // ---- chunk 1: cin 64..127 from xin (f32, no relu) ----
    for (int i = threadIdx.x; i < 4096; i += 256) wl[i] = wbase[4096 + i];
    __syncthreads();
    {
        const float* s = xin + (size_t)b * 64 * plane;
        for (int c = 0; c < 64; ++c) {
            double xa0[PX + 1], xa1[PX + 1];
#pragma unroll
            for (int j = 0; j < PX / 2; ++j) {
                float2 v0 = *(const float2*)(s + cr0 + n0 + 2 * j);
                float2 v1 = *(const float2*)(s + cr1 + n0 + 2 * j);
                xa0[ib + 2 * j] = mr0 * (double)v0.x;
                xa0[ib + 2 * j + 1] = mr0 * (double)v0.y;
                xa1[ib + 2 * j] = mr1 * (double)v1.x;
                xa1[ib + 2 * j + 1] = mr1 * (double)v1.y;
            }
            xa0[eidx] = me0 * (double)s[cr0 + eoff];
            xa1[eidx] = me1 * (double)s[cr1 + eoff];
            const double2* w2 = (const double2*)&wl[c * 64];
#pragma unroll
            for (int co = 0; co < 16; ++co) {
                double2 wa = w2[co * 2], wb = w2[co * 2 + 1];
#pragma unroll
                for (int tt = 0; tt < PX; ++tt)
                    acc[co][tt] += wa.x * xa0[tt] + wa.y * xa0[tt + 1] +
                                   wb.x * xa1[tt] + wb.y * xa1[tt + 1];
            }
            s += plane;
        }
    }

    int oy = 2 * m + ry;
    size_t ob = (size_t)(b * COUT + cog * 16) * plane * 4 + (size_t)oy * (Win * 2);
#pragma unroll
    for (int co = 0; co < 16; ++co)
#pragma unroll
        for (int tt = 0; tt < PX; ++tt)
            out[ob + (size_t)co * plane * 4 + 2 * (n0 + tt) + rx] = acc[co][tt];
}

// ---------------------------------------------------------------------------
// Fused heads (fp64) — r7-proven (LDS weight staging, broadcast double2).
// ---------------------------------------------------------------------------
__global__ __launch_bounds__(256) void head_lds_kernel(
    const double* __restrict__ z5,
    const double* __restrict__ wvT,  // [64][66] f64
    const float* __restrict__ bv,
    const double* __restrict__ wcT,  // [64][22] f64
    const float* __restrict__ bc,
    float* __restrict__ vert, double* __restrict__ dirs,
    float* __restrict__ label) {
    int p = blockIdx.x * 256 + threadIdx.x;
    int half = blockIdx.y;
    int b = blockIdx.z;
    __shared__ double wl[64 * 44];   // 22.5 KiB
    if (half == 0) {
        for (int i = threadIdx.x; i < 64 * 44; i += 256) {
            int c = i / 44, k = i - c * 44;
            wl[i] = wvT[c * 66 + k];
        }
    } else {
        for (int i = threadIdx.x; i < 64 * 44; i += 256) {
            int c = i / 44, k = i - c * 44;
            wl[i] = (k < 22) ? wvT[c * 66 + 44 + k] : wcT[c * 22 + (k - 22)];
        }
    }
    __syncthreads();

    const double* xp = z5 + (size_t)b * 64 * HW_IMG + p;
    if (half == 0) {
        double acc[44];
#pragma unroll
        for (int k = 0; k < 44; ++k) acc[k] = (double)bv[k];
        for (int c = 0; c < 64; ++c) {
            double x = fmax(xp[(size_t)c * HW_IMG], 0.0);
            const double2* w2 = (const double2*)&wl[c * 44];
#pragma unroll
            for (int j = 0; j < 22; ++j) {
                double2 w = w2[j];
                acc[2 * j] += x * w.x; acc[2 * j + 1] += x * w.y;
            }
        }
        float* op = vert + (size_t)b * 66 * HW_IMG + p;
#pragma unroll
        for (int k = 0; k < 44; ++k) op[(size_t)k * HW_IMG] = (float)acc[k];
        dirs[(size_t)b * 2 * HW_IMG + p] = acc[0];
        dirs[(size_t)b * 2 * HW_IMG + HW_IMG + p] = acc[1];
    } else {
        double acc[22], lg[22];
#pragma unroll
        for (int k = 0; k < 22; ++k) { acc[k] = (double)bv[44 + k]; lg[k] = (double)bc[k]; }
        for (int c = 0; c < 64; ++c) {
            double x = fmax(xp[(size_t)c * HW_IMG], 0.0);
            const double2* w2 = (const double2*)&wl[c * 44];
#pragma unroll
            for (int j = 0; j < 11; ++j) {
                double2 w = w2[j];
                acc[2 * j] += x * w.x; acc[2 * j + 1] += x * w.y;
            }
#pragma unroll
            for (int j = 0; j < 11; ++j) {
                double2 w = w2[11 + j];
                lg[2 * j] += x * w.x; lg[2 * j + 1] += x * w.y;
            }
        }
        float* op = vert + ((size_t)b * 66 + 44) * HW_IMG + p;
#pragma unroll
        for (int k = 0; k < 22; ++k) op[(size_t)k * HW_IMG] = (float)acc[k];
        int bi = 0; double bvv = lg[0];
#pragma unroll
        for (int k = 1; k < 22; ++k)
            if (lg[k] > bvv) { bvv = lg[k]; bi = k; }   // first max, like np.argmax
        label[(size_t)b * HW_IMG + p] = (float)bi;
    }
}

// ---------------------------------------------------------------------------
// Vote prepass (r12-proven): seg-fuse, depth/mask sums, ray params.
// ---------------------------------------------------------------------------
__global__ __launch_bounds__(256) void vote_prep_kernel(
    const float* __restrict__ seg, const float* __restrict__ depth,
    const double* __restrict__ dirs,
    double* __restrict__ rayS, double* __restrict__ rayU,
    double* __restrict__ rayV, double* __restrict__ rayRU,
    double* __restrict__ rayRV, double* __restrict__ rayN,
    double* __restrict__ sums) {
    int p = blockIdx.x * 256 + threadIdx.x;
    int b = blockIdx.z;
    double s = 0.0;
    const float* sp = seg + (size_t)b * NCLS * HW_IMG + p;
    for (int c = 0; c < NCLS; ++c) s += (double)sp[(size_t)c * HW_IMG];
    s = fmin(fmax(s, 0.0), 1.0);
    bool msk = s > 0.5;
    double d = (double)depth[(size_t)b * HW_IMG + p];
    double dm = msk ? d : 0.0;
    double mm = msk ? 1.0 : 0.0;
    for (int off = 32; off > 0; off >>= 1) {
        dm += __shfl_down(dm, off);
        mm += __shfl_down(mm, off);
    }
    __shared__ double sdm[4], smm[4];
    int wid = threadIdx.x >> 6, lane = threadIdx.x & 63;
    if (lane == 0) { sdm[wid] = dm; smm[wid] = mm; }
    __syncthreads();
    if (threadIdx.x == 0) {
        atomicAdd(&sums[b * 2 + 0], sdm[0] + sdm[1] + sdm[2] + sdm[3]);
        atomicAdd(&sums[b * 2 + 1], smm[0] + smm[1] + smm[2] + smm[3]);
    }
    size_t idx = (size_t)b * HW_IMG + p;
    if (msk) {
        double dx = dirs[(size_t)b * 2 * HW_IMG + p];
        double dy = dirs[(size_t)b * 2 * HW_IMG + HW_IMG + p];
        double nrm = sqrt(dx * dx + dy * dy) + 1e-6;
        double u = dx / nrm, v = dy / nrm;
        double xf = (double)(p % W_IMG), yf = (double)(p / W_IMG);
        double tmax = 1e30;
        if (u > 1e-9)       tmax = fmin(tmax, ((double)W_IMG - 0.25 - xf) / u);
        else if (u < -1e-9) tmax = fmin(tmax, (-0.75 - xf) / u);
        if (v > 1e-9)       tmax = fmin(tmax, ((double)H_IMG - 0.25 - yf) / v);
        else if (v < -1e-9) tmax = fmin(tmax, (-0.75 - yf) / v);
        int nst = VOTE_STEPS;
        if (tmax < (double)VOTE_STEPS) nst = (int)tmax + 1;
        rayS[idx] = s;
        rayU[idx] = u;
        rayV[idx] = v;
        rayRU[idx] = (u != 0.0) ? 1.0 / u : 0.0;
        rayRV[idx] = (v != 0.0) ? 1.0 / v : 0.0;
        rayN[idx] = (double)nst;
    } else {
        rayS[idx] = 0.0;
    }
}

// ---------------------------------------------------------------------------
// Vote tile pass (r12-proven): one 64x64 tile x one ray chunk per block;
// LDS f64 atomics; exact rint check inside conservative t-interval.
// ---------------------------------------------------------------------------
__global__ __launch_bounds__(256) void vote_tile_kernel(
    const double* __restrict__ rayS, const double* __restrict__ rayU,
    const double* __restrict__ rayV, const double* __restrict__ rayRU,
    const double* __restrict__ rayRV, const double* __restrict__ rayN,
    double* __restrict__ vparts) {
    int chunk = blockIdx.x;
    int tile = blockIdx.y;
    int b = blockIdx.z;
    int tx0 = (tile % NTX) * TW, ty0 = (tile / NTX) * TH;
    __shared__ double vt[TW * TH];   // 32 KiB
    for (int i = threadIdx.x; i < TW * TH; i += 256) vt[i] = 0.0;
    __syncthreads();

    size_t base = (size_t)b * HW_IMG;
    int p0 = chunk * CHPIX;
    for (int q = threadIdx.x; q < CHPIX; q += 256) {
        int p = p0 + q;
        double s = rayS[base + p];
        if (s == 0.0) continue;
        double u = rayU[base + p], v = rayV[base + p];
        double ru = rayRU[base + p], rv = rayRV[base + p];
        int nst = (int)rayN[base + p];
        double xf = (double)(p % W_IMG), yf = (double)(p / W_IMG);
        double ta = 1.0, tb = (double)nst;
        if (ru != 0.0) {
            double lo = ((double)(tx0 - 1) - xf) * ru;
            double hi = ((double)(tx0 + TW) - xf) * ru;
            ta = fmax(ta, fmin(lo, hi));
            tb = fmin(tb, fmax(lo, hi));
        } else {
            if (xf < (double)(tx0 - 1) || xf > (double)(tx0 + TW)) continue;
        }
        if (rv != 0.0) {
            double lo = ((double)(ty0 - 1) - yf) * rv;
            double hi = ((double)(ty0 + TH) - yf) * rv;
            ta = fmax(ta, fmin(lo, hi));
            tb = fmin(tb, fmax(lo, hi));
        } else {
            if (yf < (double)(ty0 - 1) || yf > (double)(ty0 + TH)) continue;
        }
        if (ta > tb) continue;
        int t0 = (int)ceil(ta), t1 = (int)floor(tb);
        for (int t = t0; t <= t1; ++t) {
            double tf = (double)t;
            int xi = (int)rint(xf + tf * u);   // half-to-even, like np.round
            int yi = (int)rint(yf + tf * v);
            if (xi >= tx0 && xi < tx0 + TW && yi >= ty0 && yi < ty0 + TH)
                atomicAdd(&vt[(yi - ty0) * TW + (xi - tx0)], s);
        }
    }
    __syncthreads();
    double* dst = vparts + (((size_t)chunk * 4 + b) * NTILE + tile) * (TW * TH);
    for (int i = threadIdx.x; i < TW * TH; i += 256) dst[i] = vt[i];
}

// voteacc[b][cell] = sum over chunks (fixed order) of tile partials
__global__ void vote_reduce_kernel(const double* __restrict__ vparts,
                                   double* __restrict__ voteacc,
                                   float* __restrict__ vote) {
    int i = blockIdx.x * 256 + threadIdx.x;
    if (i < 4 * HW_IMG) {
        int b = i / HW_IMG, cell = i - b * HW_IMG;
        int y = cell / W_IMG, x = cell - y * W_IMG;
        int tile = (y / TH) * NTX + (x / TW);
        int ci = (y % TH) * TW + (x % TW);
        double a = 0.0;
        for (int c = 0; c < NCHUNK; ++c)
            a += vparts[(((size_t)c * 4 + b) * NTILE + tile) * (TW * TH) + ci];
        voteacc[i] = a;
        vote[i] = (float)a;
    }
}

__global__ __launch_bounds__(1024) void center_d_kernel(
    const double* __restrict__ voteacc, const double* __restrict__ sums,
    const float* __restrict__ fx, const float* __restrict__ fy,
    const float* __restrict__ px, const float* __restrict__ py,
    float* __restrict__ centers, float* __restrict__ transl) {
    int b = blockIdx.x;
    const double* vb = voteacc + (size_t)b * HW_IMG;
    double best = -1.0;
    int bi = HW_IMG;
    for (int i = threadIdx.x; i < HW_IMG; i += 1024) {
        double v = vb[i];
        if (v > best || (v == best && i < bi)) { best = v; bi = i; }
    }
    for (int off = 32; off > 0; off >>= 1) {
        double ov = __shfl_down(best, off);
        int oi = __shfl_down(bi, off);
        if (ov > best || (ov == best && oi < bi)) { best = ov; bi = oi; }
    }
    __shared__ double sbv[16];
    __shared__ int sbi[16];
    int wid = threadIdx.x >> 6, lane = threadIdx.x & 63;
    if (lane == 0) { sbv[wid] = best; sbi[wid] = bi; }
    __syncthreads();
    if (threadIdx.x == 0) {
        for (int q = 1; q < 16; ++q)
            if (sbv[q] > best || (sbv[q] == best && sbi[q] < bi)) {
                best = sbv[q]; bi = sbi[q];
            }
        double cx = (double)(bi % W_IMG), cy = (double)(bi / W_IMG);
        double tz = sums[b * 2 + 0] / (sums[b * 2 + 1] + 1e-6);
        double tx = (cx - (double)px[0]) * tz / (double)fx[0];
        double ty = (cy - (double)py[0]) * tz / (double)fy[0];
        centers[b * 2 + 0] = (float)cx;
        centers[b * 2 + 1] = (float)cy;
        transl[b * 3 + 0] = (float)tx;
        transl[b * 3 + 1] = (float)ty;
        transl[b * 3 + 2] = (float)tz;
    }
}

// ---------------------------------------------------------------------------
extern "C" void kernel_launch(void* const* d_in, const int* in_sizes, int n_in,
                              void* d_out, int out_size, void* d_ws, size_t ws_size,
                              hipStream_t stream) {
    const float* x1 = (const float*)d_in[0];
    const float* x2 = (const float*)d_in[1];
    const float* x3 = (const float*)d_in[2];
    const float* x4 = (const float*)d_in[3];
    const float* x5 = (const float*)d_in[4];
    const float* depth = (const float*)d_in[5];
    const float* seg = (const float*)d_in[6];
    const float* fx = (const float*)d_in[7];
    const float* fy = (const float*)d_in[8];
    const float* px = (const float*)d_in[9];
    const float* py = (const float*)d_in[10];
    const float* w5 = (const float*)d_in[11];
    const float* b5 = (const float*)d_in[12];
    const float* w4 = (const float*)d_in[13];
    const float* b4 = (const float*)d_in[14];
    const float* w3 = (const float*)d_in[15];
    const float* b3 = (const float*)d_in[16];
    const float* w2 = (const float*)d_in[17];
    const float* b2 = (const float*)d_in[18];
    const float* w1 = (const float*)d_in[19];
    const float* b1 = (const float*)d_in[20];
    const float* wv = (const float*)d_in[21];
    const float* bv = (const float*)d_in[22];
    const float* wc = (const float*)d_in[23];
    const float* bc = (const float*)d_in[24];

    // output layout (flat f32, reference return order)
    float* out = (float*)d_out;
    float* vert = out;                               // [4,66,256,320]
    float* label = vert + (size_t)4 * 66 * HW_IMG;   // [4,256,320]
    float* vote = label + (size_t)4 * HW_IMG;        // [4,256,320]
    float* centers = vote + (size_t)4 * HW_IMG;      // [4,2]
    float* transl = centers + 8;                     // [4,3]

    // workspace layout (all f64) — identical extent to r7/r12 (proven).
    double* zA = (double*)d_ws;            // 20,971,520
    double* zB = zA + 20971520;            //  5,242,880
    double* dirs = zB + 5242880;           //    655,360
    double* voteacc = dirs + 655360;       //    327,680
    double* sums = voteacc + 327680;       //          8
    double* wp5 = sums + 8;                // 2,097,152  [4][512][256][4]
    double* wp4 = wp5 + 2097152;           // 1,048,576  [4][512][128][4]
    double* wp3 = wp4 + 1048576;           //   262,144  [4][256][64][4]
    double* wr2 = wp3 + 262144;            //   131,072  [4][4][128][16][4]
    double* wr1 = wr2 + 131072;            //   131,072  [4][4][128][16][4]
    double* wvT = wr1 + 131072;            //     4,224
    double* wcT = wvT + 4224;              //     1,408
    double* z1 = zA; double* z2 = zB; double* z3 = zA; double* z4 = zB; double* z5 = zA;
    // conv partial-sum scratch (r10-proven): dead zA interior [2M, 7.25M)
    // L1 needs 16 x 327,680 = 5,242,880 -> [2M, 7.243M) ok, disjoint from z1.
    double* parts = zA + 2000000;
    // ray arrays: zB is dead after L5 (z4 consumed)
    double* rayS = zB;                     // 327,680 each
    double* rayU = zB + 327680;
    double* rayV = zB + 2 * 327680;
    double* rayRU = zB + 3 * 327680;
    double* rayRV = zB + 4 * 327680;
    double* rayN = zB + 5 * 327680;        // total 1.97M <= 5.24M ok
    // vote tile partials: zA (z5) is dead after heads; 16*4*20*4096 = 5.24M
    double* vparts = zA;

    hipMemsetAsync(sums, 0, 8 * sizeof(double), stream);

    // weight repacks
    auto rp = [&](const float* w, double* wp, int CIN, int COUT) {
        int total = CIN * COUT * 16;
        repack_kernel<<<(total + 255) / 256, 256, 0, stream>>>(w, wp, CIN, COUT);
    };
    rp(w5, wp5, 512, 256);
    rp(w4, wp4, 512, 128);
    rp(w3, wp3, 256, 64);
    repackR_kernel<<<(131072 + 255) / 256, 256, 0, stream>>>(w2, wr2, 128, 64);
    repackR_kernel<<<(131072 + 255) / 256, 256, 0, stream>>>(w1, wr1, 128, 64);
    transpose_d_kernel<<<(66 * 64 + 255) / 256, 256, 0, stream>>>(wv, wvT, 66, 64);
    transpose_d_kernel<<<(22 * 64 + 255) / 256, 256, 0, stream>>>(wc, wcT, 22, 64);

    // L1: x1[4,512,8,10] -> z1[4,256,16,20], merged-parity block=320,
    //     split 16 (cinPer 32), partial+reduce
    convt_part_l1_kernel<<<dim3(1, 16, 64), 320, 0, stream>>>(
        x1, 512, wp5, parts, 256, 16, 4, 327680);
    reduce_part_kernel<<<1280, 256, 0, stream>>>(parts, b5, z1, 16, 256, 320, 327680);
    // L2: [relu(z1)|x2] -> z2[4,128,32,40], block=320 (=plane), split 8
    convt_part_kernel<true, true><<<dim3(1, 32, 32), 320, 0, stream>>>(
        z1, 256, x2, 256, wp4, parts, 128, 16, 20, 8, 4, 655360);
    reduce_part_kernel<<<2560, 256, 0, stream>>>(parts, b4, z2, 8, 128, 1280, 655360);
    // L3: [relu(z2)|x3] -> z3[4,64,64,80], split 4, block=256 (plane=1280)
    convt_part_kernel<true, true><<<dim3(5, 16, 16), 256, 0, stream>>>(
        z2, 128, x3, 128, wp3, parts, 64, 32, 40, 4, 4, 1310720);
    reduce_part_kernel<<<5120, 256, 0, stream>>>(parts, b3, z3, 4, 64, 5120, 1310720);
    // L4: [relu(z3)|x4] -> z4[4,64,128,160]  (r12 16co x 2px tile)
    convt_reg_kernel<2><<<dim3(10, 16, 4), 256, 0, stream>>>(
        z3, x4, wr2, b2, z4, 64, 64, 80);
    // L5: [relu(z4)|x5] -> z5[4,64,256,320]  (r12 16co x 2px tile)
    convt_reg_kernel<2><<<dim3(40, 16, 4), 256, 0, stream>>>(
        z4, x5, wr1, b1, z5, 64, 128, 160);

    // fused heads (r7-proven)
    head_lds_kernel<<<dim3(320, 2, 4), 256, 0, stream>>>(z5, wvT, bv, wcT, bc,
                                                         vert, dirs, label);

    // hough voting: prepass -> LDS-tiled accumulate -> reduce -> center
    vote_prep_kernel<<<dim3(320, 1, 4), 256, 0, stream>>>(
        seg, depth, dirs, rayS, rayU, rayV, rayRU, rayRV, rayN, sums);
    vote_tile_kernel<<<dim3(NCHUNK, NTILE, 4), 256, 0, stream>>>(
        rayS, rayU, rayV, rayRU, rayRV, rayN, vparts);
    vote_reduce_kernel<<<(4 * HW_IMG + 255) / 256, 256, 0, stream>>>(
        vparts, voteacc, vote);
    center_d_kernel<<<4, 1024, 0, stream>>>(voteacc, sums, fx, fy, px, py,
                                            centers, transl);
}